// Round 13
// baseline (175.229 us; speedup 1.0000x reference)
//
#include <hip/hip_runtime.h>
#include <math.h>

typedef unsigned short ushort_t;
typedef unsigned int uint_t;
typedef float  float4_t  __attribute__((ext_vector_type(4)));
typedef short  short8_t  __attribute__((ext_vector_type(8)));
typedef short  short4_t  __attribute__((ext_vector_type(4)));

static constexpr int B_   = 2;
static constexpr int S_   = 64;
static constexpr int N_   = 48;
static constexpr int D_   = 128;
static constexpr int H_   = 8;
static constexpr int DH_  = 16;
static constexpr int L_   = S_ * N_;        // 3072
static constexpr int TOK_ = B_ * L_;        // 6144
static constexpr int F_   = TOK_ * D_;      // 786432

__device__ __forceinline__ uint_t bf16rne(float f) {
  uint_t u = __float_as_uint(f);
  return (u + 0x7fffu + ((u >> 16) & 1u)) >> 16;
}
__device__ __forceinline__ uint_t cvtpk_bf16(float lo, float hi) {
  uint_t r;
  asm("v_cvt_pk_bf16_f32 %0, %1, %2" : "=v"(r) : "v"(lo), "v"(hi));
  return r;
}
__device__ __forceinline__ float sigmoidf_(float z) {
  return 1.0f / (1.0f + __expf(-z));
}

// ---------------------------------------------------------------------------
// K0: merged prep. Block ranges:
//   [0,3072)      posadd: xpe = x + spos + tpos
//   [3072,4096)   conv weight prep -> wprep
//   [4096,4288)   spatial weight prep -> wsp
//   [4288,4928)   final+qkv weight prep -> wfin
//   [4928]        adjacency prep -> apb (per-block barriers; 256 threads)
// ---------------------------------------------------------------------------
__global__ void k_prep(const float* __restrict__ x, const float* __restrict__ sp,
                       const float* __restrict__ tp, float* __restrict__ xpe,
                       const float* __restrict__ w1, const float* __restrict__ w3,
                       const float* __restrict__ w5, const float* __restrict__ w7,
                       ushort_t* __restrict__ wprep,
                       const float* __restrict__ sw0, const float* __restrict__ sw1,
                       const float* __restrict__ sw2, ushort_t* __restrict__ wsp,
                       const float* __restrict__ wo, const float* __restrict__ gsp,
                       const float* __restrict__ gtm, const float* __restrict__ gfu,
                       const float* __restrict__ wIn, ushort_t* __restrict__ wfin,
                       const float* __restrict__ adj, ushort_t* __restrict__ apb) {
  __shared__ float degl[48];
  __shared__ float a1[2304];
  __shared__ float a2[2304];
  int blk = blockIdx.x;
  int tid = threadIdx.x;
  if (blk < 3072) {
    int idx = blk * 256 + tid;
    int d  = idx & 127;
    int t2 = idx >> 7;
    int n  = t2 % 48;
    int t3 = t2 / 48;
    int s  = t3 & 63;
    xpe[idx] = x[idx] + sp[n * 128 + d] + tp[s * 128 + d];
  } else if (blk < 4096) {
    int idx = (blk - 3072) * 256 + tid;    // 0..262143
    int p = idx >> 14;
    int rem = idx & 16383;
    int c = rem >> 7, i = rem & 127;
    float v;
    if (p == 0)       v = w1[c * 128 + i];
    else if (p < 4)   v = w3[(c * 128 + i) * 3 + (p - 1)];
    else if (p < 9)   v = w5[(c * 128 + i) * 5 + (p - 4)];
    else              v = w7[(c * 128 + i) * 7 + (p - 9)];
    wprep[idx] = (ushort_t)bf16rne(v);
  } else if (blk < 4288) {
    int idx = (blk - 4096) * 256 + tid;    // 0..49151
    int hop = idx >> 14, r = idx & 16383;
    const float* W = (hop == 0) ? sw0 : ((hop == 1) ? sw1 : sw2);
    wsp[idx] = (ushort_t)bf16rne(W[r]);
  } else if (blk < 4928) {
    int idx = (blk - 4288) * 256 + tid;    // 0..163839
    float v;
    if (idx < 16384)       v = wo[idx];
    else if (idx < 49152)  v = gsp[idx - 16384];
    else if (idx < 81920)  v = gtm[idx - 49152];
    else if (idx < 114688) v = gfu[idx - 81920];
    else                   v = wIn[idx - 114688];
    wfin[idx] = (ushort_t)bf16rne(v);
  } else {
    // adjacency prep (single block, 256 threads)
    if (tid < 48) {
      float s = 0.f;
      for (int n = 0; n < 48; n++) s += adj[tid * 48 + n];
      degl[tid] = (s == 0.0f) ? 1.0f : s;
    }
    __syncthreads();
    for (int e = tid; e < 2304; e += 256) {
      float v = adj[e] / degl[e / 48];
      a1[e] = v;
      apb[(e / 48) * 64 + (e % 48)] = (ushort_t)bf16rne(v);
    }
    __syncthreads();
    for (int e = tid; e < 2304; e += 256) {
      int m = e / 48, n = e % 48;
      float s = 0.f;
      for (int k2 = 0; k2 < 48; k2++) s += a1[m * 48 + k2] * a1[k2 * 48 + n];
      a2[e] = s;
      apb[3072 + m * 64 + n] = (ushort_t)bf16rne(s);
    }
    __syncthreads();
    for (int e = tid; e < 2304; e += 256) {
      int m = e / 48, n = e % 48;
      float s = 0.f;
      for (int k2 = 0; k2 < 48; k2++) s += a2[m * 48 + k2] * a1[k2 * 48 + n];
      apb[6144 + m * 64 + n] = (ushort_t)bf16rne(s);
    }
    for (int e = tid; e < 2304; e += 256) {
      int hop = e / 768, rem = e % 768;
      apb[hop * 3072 + (rem / 16) * 64 + 48 + (rem % 16)] = 0;
    }
  }
}

// ---------------------------------------------------------------------------
// K2: MFMA implicit-GEMM conv (unchanged, proven)
// ---------------------------------------------------------------------------
__global__ __launch_bounds__(256) void k_conv_mfma(
    const float* __restrict__ xpe, const ushort_t* __restrict__ wprep,
    const float* __restrict__ b1, const float* __restrict__ b3,
    const float* __restrict__ b5, const float* __restrict__ b7,
    float* __restrict__ out) {
  __shared__ ushort_t xl[38 * 128];
  char* xlb = (char*)xl;
  int blk = blockIdx.x;
  int bn = blk >> 2, chalf = (blk >> 1) & 1, thalf = blk & 1;
  int b = bn / 48, node = bn % 48;
  int t0 = thalf * 32;
  int tid = threadIdx.x;

  for (int seg = tid; seg < 608; seg += 256) {
    int row = seg >> 4, sidx = seg & 15;
    int gt = t0 + row - 3;
    int dst = row * 256 + ((sidx * 16) ^ ((row & 7) << 4));
    uint4 pk = make_uint4(0, 0, 0, 0);
    if (gt >= 0 && gt < 64) {
      const float* src = xpe + ((size_t)((b * 64 + gt) * 48 + node)) * 128 + sidx * 8;
      float4 f0 = ((const float4*)src)[0];
      float4 f1 = ((const float4*)src)[1];
      pk.x = bf16rne(f0.x) | (bf16rne(f0.y) << 16);
      pk.y = bf16rne(f0.z) | (bf16rne(f0.w) << 16);
      pk.z = bf16rne(f1.x) | (bf16rne(f1.y) << 16);
      pk.w = bf16rne(f1.z) | (bf16rne(f1.w) << 16);
    }
    *(uint4*)(xlb + dst) = pk;
  }
  __syncthreads();

  int w = tid >> 6, lane = tid & 63;
  int i16 = lane & 15, grp = lane >> 4;
  int grpoff = grp * 16;
  int c0 = chalf * 64 + w * 16;

  float4_t acc[4][2];
#pragma unroll
  for (int cv = 0; cv < 4; cv++)
#pragma unroll
    for (int tm = 0; tm < 2; tm++) acc[cv][tm] = (float4_t){0.f, 0.f, 0.f, 0.f};

  const int cid[16] = {0, 1, 1, 1, 2, 2, 2, 2, 2, 3, 3, 3, 3, 3, 3, 3};
  const int shf[16] = {0, -1, 0, 1, -2, -1, 0, 1, 2, -3, -2, -1, 0, 1, 2, 3};

#pragma unroll
  for (int p = 0; p < 16; p++) {
    int rb0 = 3 + shf[p] + i16;
#pragma unroll
    for (int ks = 0; ks < 4; ks++) {
      short8_t bfr = *(const short8_t*)(wprep + ((size_t)(p * 128 + c0 + i16)) * 128 + ks * 32 + grp * 8);
#pragma unroll
      for (int tm = 0; tm < 2; tm++) {
        int row = rb0 + tm * 16;
        int off = row * 256 + ((ks * 64 + grpoff) ^ ((row & 7) << 4));
        short8_t afr = *(const short8_t*)(xlb + off);
        acc[cid[p]][tm] = __builtin_amdgcn_mfma_f32_16x16x32_bf16(afr, bfr, acc[cid[p]][tm], 0, 0, 0);
      }
    }
  }

  int c = c0 + i16;
  float bias0 = b1[c], bias1 = b3[c], bias2 = b5[c], bias3 = b7[c];
#pragma unroll
  for (int tm = 0; tm < 2; tm++) {
#pragma unroll
    for (int r = 0; r < 4; r++) {
      int t = t0 + tm * 16 + grp * 4 + r;
      size_t gidx = ((size_t)((b * 64 + t) * 48 + node)) * 128 + c;
      float v = fmaxf(acc[0][tm][r] + bias0, 0.f) + fmaxf(acc[1][tm][r] + bias1, 0.f)
              + fmaxf(acc[2][tm][r] + bias2, 0.f) + fmaxf(acc[3][tm][r] + bias3, 0.f);
      out[gidx] = v * 0.25f + xpe[gidx];
    }
  }
}

// ---------------------------------------------------------------------------
// K3: LayerNorm (ln1 only now). 4 rows/block (1 wave each).
// ---------------------------------------------------------------------------
__global__ void k_ln(const float* __restrict__ in, float* __restrict__ outp,
                     const float* __restrict__ g, const float* __restrict__ bb) {
  int row  = blockIdx.x * 4 + (threadIdx.x >> 6);
  int lane = threadIdx.x & 63;
  const float* r = in + row * 128;
  float v0 = r[lane], v1 = r[lane + 64];
  float s = v0 + v1;
#pragma unroll
  for (int m = 32; m; m >>= 1) s += __shfl_xor(s, m);
  float mean = s * (1.0f / 128.0f);
  float d0 = v0 - mean, d1 = v1 - mean;
  float q = d0 * d0 + d1 * d1;
#pragma unroll
  for (int m = 32; m; m >>= 1) q += __shfl_xor(q, m);
  float rstd = rsqrtf(q * (1.0f / 128.0f) + 1e-5f);
  outp[row * 128 + lane]      = d0 * rstd * g[lane]      + bb[lane];
  outp[row * 128 + lane + 64] = d1 * rstd * g[lane + 64] + bb[lane + 64];
}

// ---------------------------------------------------------------------------
// K4: MFMA spatial branch + FUSED LN2. Body identical to the proven version
// (XT/Cl now live in one aliased smem block with the same byte offsets).
// After the hop loop: barrier -> write sacc/3 + x (fp32) into the dead
// XT+Cl space -> per-wave 12-row LN (k_ln math) -> write `spatial` directly.
// ---------------------------------------------------------------------------
__global__ __launch_bounds__(256) void k_spatial_mfma(
    const float* __restrict__ xpe, const ushort_t* __restrict__ apb,
    const ushort_t* __restrict__ wsp,
    const float* __restrict__ bb0, const float* __restrict__ bb1,
    const float* __restrict__ bb2,
    const float* __restrict__ lng, const float* __restrict__ lnb,
    float* __restrict__ outp) {
  __shared__ char smem[28672];       // [0,16384): XT, [16384,28672): Cl
  char* XTb = smem;
  char* Clb = smem + 16384;
  int bs = blockIdx.x;
  int tid = threadIdx.x;
  const float* xrow = xpe + (size_t)bs * 6144;

  for (int e = tid; e < 1024; e += 256)
    *(uint4*)(XTb + e * 16) = make_uint4(0, 0, 0, 0);
  __syncthreads();
  for (int e = tid; e < 1536; e += 256) {
    int node = e % 48, dq = e / 48;
    float4 xv = *(const float4*)(xrow + node * 128 + dq * 4);
    int d0 = dq * 4;
    *(ushort_t*)(XTb + (((d0 + 0) * 128 + node * 2) ^ (((d0 + 0) & 7) << 4))) = (ushort_t)bf16rne(xv.x);
    *(ushort_t*)(XTb + (((d0 + 1) * 128 + node * 2) ^ (((d0 + 1) & 7) << 4))) = (ushort_t)bf16rne(xv.y);
    *(ushort_t*)(XTb + (((d0 + 2) * 128 + node * 2) ^ (((d0 + 2) & 7) << 4))) = (ushort_t)bf16rne(xv.z);
    *(ushort_t*)(XTb + (((d0 + 3) * 128 + node * 2) ^ (((d0 + 3) & 7) << 4))) = (ushort_t)bf16rne(xv.w);
  }
  __syncthreads();

  int w = tid >> 6, lane = tid & 63;
  int i16 = lane & 15, g = lane >> 4;

  float4_t sacc[3][2];
#pragma unroll
  for (int mt = 0; mt < 3; mt++)
#pragma unroll
    for (int nt = 0; nt < 2; nt++) sacc[mt][nt] = (float4_t){0.f, 0.f, 0.f, 0.f};

  for (int hop = 0; hop < 3; hop++) {
    float4_t c1[2][3];
#pragma unroll
    for (int mt = 0; mt < 2; mt++)
#pragma unroll
      for (int nt = 0; nt < 3; nt++) c1[mt][nt] = (float4_t){0.f, 0.f, 0.f, 0.f};
#pragma unroll
    for (int kt = 0; kt < 2; kt++) {
#pragma unroll
      for (int mt = 0; mt < 2; mt++) {
        int arow = (w * 2 + mt) * 16 + i16;
        short8_t af = *(const short8_t*)(XTb + ((arow * 128 + (kt * 32 + 8 * g) * 2) ^ ((arow & 7) << 4)));
#pragma unroll
        for (int nt = 0; nt < 3; nt++) {
          short8_t bf = *(const short8_t*)(apb + hop * 3072 + (nt * 16 + i16) * 64 + kt * 32 + 8 * g);
          c1[mt][nt] = __builtin_amdgcn_mfma_f32_16x16x32_bf16(af, bf, c1[mt][nt], 0, 0, 0);
        }
      }
    }
    __syncthreads();
#pragma unroll
    for (int mt = 0; mt < 2; mt++) {
#pragma unroll
      for (int nt = 0; nt < 3; nt++) {
        int node = nt * 16 + i16;
        int d0 = (w * 2 + mt) * 16 + 4 * g;
        uint_t lo = cvtpk_bf16(c1[mt][nt][0], c1[mt][nt][1]);
        uint_t hi = cvtpk_bf16(c1[mt][nt][2], c1[mt][nt][3]);
        *(uint2*)(Clb + ((node * 256 + d0 * 2) ^ ((node & 7) << 4))) = make_uint2(lo, hi);
      }
    }
    __syncthreads();
    float4_t c2[3][2];
#pragma unroll
    for (int mt = 0; mt < 3; mt++)
#pragma unroll
      for (int nt = 0; nt < 2; nt++) c2[mt][nt] = (float4_t){0.f, 0.f, 0.f, 0.f};
#pragma unroll
    for (int kt = 0; kt < 4; kt++) {
#pragma unroll
      for (int mt = 0; mt < 3; mt++) {
        int arow = mt * 16 + i16;
        short8_t af = *(const short8_t*)(Clb + ((arow * 256 + (kt * 32 + 8 * g) * 2) ^ ((arow & 7) << 4)));
#pragma unroll
        for (int nt = 0; nt < 2; nt++) {
          int o = (w * 2 + nt) * 16 + i16;
          short8_t bf = *(const short8_t*)(wsp + ((size_t)(hop * 128 + o)) * 128 + kt * 32 + 8 * g);
          c2[mt][nt] = __builtin_amdgcn_mfma_f32_16x16x32_bf16(af, bf, c2[mt][nt], 0, 0, 0);
        }
      }
    }
    const float* Bs = (hop == 0) ? bb0 : ((hop == 1) ? bb1 : bb2);
#pragma unroll
    for (int nt = 0; nt < 2; nt++) {
      float bi = Bs[(w * 2 + nt) * 16 + i16];
#pragma unroll
      for (int mt = 0; mt < 3; mt++)
#pragma unroll
        for (int r = 0; r < 4; r++)
          sacc[mt][nt][r] += fmaxf(c2[mt][nt][r] + bi, 0.f);
    }
  }

  // ---- fused LN2 ----
  __syncthreads();                         // all GEMM2 reads of XT/Cl complete
  float* F = (float*)smem;                 // [48][128] fp32 = 24576 B
#pragma unroll
  for (int mt = 0; mt < 3; mt++) {
#pragma unroll
    for (int nt = 0; nt < 2; nt++) {
#pragma unroll
      for (int r = 0; r < 4; r++) {
        int node = mt * 16 + 4 * g + r;
        int o = (w * 2 + nt) * 16 + i16;
        F[node * 128 + o] = sacc[mt][nt][r] * (1.0f / 3.0f) + xrow[node * 128 + o];
      }
    }
  }
  __syncthreads();
  float* orow = outp + (size_t)bs * 6144;
  for (int rr = 0; rr < 12; rr++) {
    int row = w * 12 + rr;
    float v0 = F[row * 128 + lane], v1 = F[row * 128 + lane + 64];
    float s = v0 + v1;
#pragma unroll
    for (int m = 32; m; m >>= 1) s += __shfl_xor(s, m);
    float mean = s * (1.0f / 128.0f);
    float d0 = v0 - mean, d1 = v1 - mean;
    float q = d0 * d0 + d1 * d1;
#pragma unroll
    for (int m = 32; m; m >>= 1) q += __shfl_xor(q, m);
    float rstd = rsqrtf(q * (1.0f / 128.0f) + 1e-5f);
    orow[row * 128 + lane]      = d0 * rstd * lng[lane]      + lnb[lane];
    orow[row * 128 + lane + 64] = d1 * rstd * lng[lane + 64] + lnb[lane + 64];
  }
}

// ---------------------------------------------------------------------------
// K6: MFMA QKV projections + fused inter (unchanged, proven)
// ---------------------------------------------------------------------------
__global__ __launch_bounds__(256) void k_qkv_mfma(
    const float* __restrict__ temporal, const float* __restrict__ spatial,
    const ushort_t* __restrict__ wqkv, const float* __restrict__ bIn,
    const float* __restrict__ iw,
    ushort_t* __restrict__ qb, ushort_t* __restrict__ kb, ushort_t* __restrict__ vtb,
    float* __restrict__ interp) {
  __shared__ ushort_t bufT[32 * 128];
  __shared__ ushort_t bufS[32 * 128];
  char* T_ = (char*)bufT;
  char* S_ = (char*)bufS;
  int tok0 = blockIdx.x * 32;
  int tid = threadIdx.x;

  for (int seg = tid; seg < 512; seg += 256) {
    int row = seg >> 4, c8 = (seg & 15) * 8;
    int dst = (row * 256 + c8 * 2) ^ ((row & 7) << 4);
    size_t gbase = (size_t)(tok0 + row) * 128 + c8;
    {
      float4 f0 = *(const float4*)(temporal + gbase);
      float4 f1 = *(const float4*)(temporal + gbase + 4);
      *(uint4*)(T_ + dst) = make_uint4(cvtpk_bf16(f0.x, f0.y), cvtpk_bf16(f0.z, f0.w),
                                       cvtpk_bf16(f1.x, f1.y), cvtpk_bf16(f1.z, f1.w));
    }
    {
      float4 f0 = *(const float4*)(spatial + gbase);
      float4 f1 = *(const float4*)(spatial + gbase + 4);
      *(uint4*)(S_ + dst) = make_uint4(cvtpk_bf16(f0.x, f0.y), cvtpk_bf16(f0.z, f0.w),
                                       cvtpk_bf16(f1.x, f1.y), cvtpk_bf16(f1.z, f1.w));
    }
  }
  __syncthreads();

  int w = tid >> 6, lane = tid & 63;
  int i16 = lane & 15, g = lane >> 4;
  int mt = w >> 1, nh = w & 1;
  int mrow = mt * 16 + i16;
  int b = tok0 / 3072, l0 = tok0 % 3072;
  const float QSCALE = 0.25f * 1.4426950408889634f;

  float4_t accQ[4], accK[4], accV[4];
#pragma unroll
  for (int nt = 0; nt < 4; nt++) {
    accQ[nt] = (float4_t){0.f, 0.f, 0.f, 0.f};
    accK[nt] = (float4_t){0.f, 0.f, 0.f, 0.f};
    accV[nt] = (float4_t){0.f, 0.f, 0.f, 0.f};
  }

#pragma unroll
  for (int kt = 0; kt < 4; kt++) {
    short8_t af = *(const short8_t*)(T_ + ((mrow * 256 + (kt * 32 + 8 * g) * 2) ^ ((mrow & 7) << 4)));
#pragma unroll
    for (int nt = 0; nt < 4; nt++) {
      int o = nh * 64 + nt * 16 + i16;
      short8_t bf = *(const short8_t*)(wqkv + (size_t)o * 128 + kt * 32 + 8 * g);
      accQ[nt] = __builtin_amdgcn_mfma_f32_16x16x32_bf16(af, bf, accQ[nt], 0, 0, 0);
    }
  }
#pragma unroll
  for (int kt = 0; kt < 4; kt++) {
    short8_t af = *(const short8_t*)(S_ + ((mrow * 256 + (kt * 32 + 8 * g) * 2) ^ ((mrow & 7) << 4)));
#pragma unroll
    for (int nt = 0; nt < 4; nt++) {
      int o = nh * 64 + nt * 16 + i16;
      short8_t bfk = *(const short8_t*)(wqkv + (size_t)(128 + o) * 128 + kt * 32 + 8 * g);
      short8_t bfv = *(const short8_t*)(wqkv + (size_t)(256 + o) * 128 + kt * 32 + 8 * g);
      accK[nt] = __builtin_amdgcn_mfma_f32_16x16x32_bf16(af, bfk, accK[nt], 0, 0, 0);
      accV[nt] = __builtin_amdgcn_mfma_f32_16x16x32_bf16(af, bfv, accV[nt], 0, 0, 0);
    }
  }

#pragma unroll
  for (int nt = 0; nt < 4; nt++) {
    int o = nh * 64 + nt * 16 + i16;
    int h = o >> 4, dh = o & 15;
    int bh = b * 8 + h;
    float bq = bIn[o], bk = bIn[128 + o], bv = bIn[256 + o];
#pragma unroll
    for (int r = 0; r < 4; r++) {
      int l = l0 + mt * 16 + 4 * g + r;
      qb[((size_t)bh * 3072 + l) * 16 + dh] = (ushort_t)bf16rne((accQ[nt][r] + bq) * QSCALE);
      kb[((size_t)bh * 3072 + l) * 16 + dh] = (ushort_t)bf16rne(accK[nt][r] + bk);
      vtb[((size_t)bh * 16 + dh) * 3072 + l] = (ushort_t)bf16rne(accV[nt][r] + bv);
    }
  }

  // fused inter: o = tid&127, token rows (tid>>7)*16 .. +15
  {
    int o = tid & 127, th = tid >> 7;
    int jb = o & ~15;
    float W[16];
    const float4* W4 = (const float4*)(iw + o * 16);
#pragma unroll
    for (int j4 = 0; j4 < 4; j4++) {
      float4 wv = W4[j4];
      W[j4 * 4 + 0] = wv.x; W[j4 * 4 + 1] = wv.y;
      W[j4 * 4 + 2] = wv.z; W[j4 * 4 + 3] = wv.w;
    }
    for (int tk = 0; tk < 16; tk++) {
      int row = th * 16 + tk;
      int sw = (row & 7) << 4;
      uint4 h0 = *(const uint4*)(S_ + ((row * 256 + jb * 2) ^ sw));
      uint4 h1 = *(const uint4*)(S_ + ((row * 256 + jb * 2 + 16) ^ sw));
      uint_t su[8] = {h0.x, h0.y, h0.z, h0.w, h1.x, h1.y, h1.z, h1.w};
      float s = 0.f;
#pragma unroll
      for (int j = 0; j < 8; j++) {
        float lo = __uint_as_float(su[j] << 16);
        float hi = __uint_as_float(su[j] & 0xFFFF0000u);
        s += W[2 * j] * lo + W[2 * j + 1] * hi;
      }
      uint_t tu = *(const ushort_t*)(T_ + ((row * 256 + o * 2) ^ sw));
      float tv = __uint_as_float((uint_t)tu << 16);
      interp[(size_t)(tok0 + row) * 128 + o] = tv * s;
    }
  }
}

// ---------------------------------------------------------------------------
// K7: MFMA flash attention v2 — VERBATIM proven version. DO NOT MODIFY.
// ---------------------------------------------------------------------------
#define ATTN_CORE(K0, K1, V0, V1)                                                    \
  {                                                                                  \
    float4_t S0 = __builtin_amdgcn_mfma_f32_16x16x32_bf16(K0, qf, (float4_t){0.f,0.f,0.f,0.f}, 0, 0, 0); \
    float4_t S1 = __builtin_amdgcn_mfma_f32_16x16x32_bf16(K1, qf, (float4_t){0.f,0.f,0.f,0.f}, 0, 0, 0); \
    float p0 = exp2f(S0[0]), p1 = exp2f(S0[1]), p2 = exp2f(S0[2]), p3 = exp2f(S0[3]); \
    float p4 = exp2f(S1[0]), p5 = exp2f(S1[1]), p6 = exp2f(S1[2]), p7 = exp2f(S1[3]); \
    lsum += ((p0 + p1) + (p2 + p3)) + ((p4 + p5) + (p6 + p7));                       \
    union { uint_t u[4]; short8_t s; } pp;                                           \
    pp.u[0] = cvtpk_bf16(p0, p1); pp.u[1] = cvtpk_bf16(p2, p3);                      \
    pp.u[2] = cvtpk_bf16(p4, p5); pp.u[3] = cvtpk_bf16(p6, p7);                      \
    union { short4_t s4[2]; short8_t s8; } vv; vv.s4[0] = V0; vv.s4[1] = V1;         \
    Ot = __builtin_amdgcn_mfma_f32_16x16x32_bf16(vv.s8, pp.s, Ot, 0, 0, 0);          \
  }

__global__ __launch_bounds__(256) void k_attn_mfma(
    const ushort_t* __restrict__ qb, const ushort_t* __restrict__ kb,
    const ushort_t* __restrict__ vtb, float* __restrict__ aob) {
  int blk = blockIdx.x;
  int bh = blk / 48, qt = blk % 48;
  int w = threadIdx.x >> 6, lane = threadIdx.x & 63;
  int i16 = lane & 15, g = lane >> 4;
  int q = qt * 64 + w * 16 + i16;

  const ushort_t* qbase = qb + (size_t)bh * 3072 * 16;
  const ushort_t* kfp = kb + (size_t)bh * 3072 * 16 + i16 * 16 + (g & 1) * 8;
  const ushort_t* vrow = vtb + ((size_t)bh * 16 + i16) * 3072 + 4 * g;

  short8_t qf = {0, 0, 0, 0, 0, 0, 0, 0};
  if (g < 2) qf = *(const short8_t*)(qbase + q * 16 + g * 8);

  float4_t Ot = {0.f, 0.f, 0.f, 0.f};
  float lsum = 0.f;

  short8_t kA0 = *(const short8_t*)(kfp + 0);
  short8_t kA1 = *(const short8_t*)(kfp + 256);
  short4_t vA0 = *(const short4_t*)(vrow + 0);
  short4_t vA1 = *(const short4_t*)(vrow + 16);
  short8_t kB0 = *(const short8_t*)(kfp + 512);
  short8_t kB1 = *(const short8_t*)(kfp + 768);
  short4_t vB0 = *(const short4_t*)(vrow + 32);
  short4_t vB1 = *(const short4_t*)(vrow + 48);

  for (int kt = 0; kt < 3072; kt += 64) {
    {
      short8_t k0 = kA0, k1 = kA1; short4_t v0 = vA0, v1 = vA1;
      int pt = kt + 64;
      kA0 = *(const short8_t*)(kfp + pt * 16);
      kA1 = *(const short8_t*)(kfp + pt * 16 + 256);
      vA0 = *(const short4_t*)(vrow + pt);
      vA1 = *(const short4_t*)(vrow + pt + 16);
      ATTN_CORE(k0, k1, v0, v1);
    }
    {
      short8_t k0 = kB0, k1 = kB1; short4_t v0 = vB0, v1 = vB1;
      int pt = kt + 96;
      kB0 = *(const short8_t*)(kfp + pt * 16);
      kB1 = *(const short8_t*)(kfp + pt * 16 + 256);
      vB0 = *(const short4_t*)(vrow + pt);
      vB1 = *(const short4_t*)(vrow + pt + 16);
      ATTN_CORE(k0, k1, v0, v1);
    }
  }

  lsum += __shfl_xor(lsum, 16);
  lsum += __shfl_xor(lsum, 32);
  float inv = 1.0f / lsum;
  int b = bh >> 3, h = bh & 7;
  float* orow = aob + ((size_t)b * 3072 + q) * 128 + h * 16;
#pragma unroll
  for (int r = 0; r < 4; r++) orow[4 * g + r] = Ot[r] * inv;
}

// ---------------------------------------------------------------------------
// K8: MFMA final stage (unchanged, proven)
// ---------------------------------------------------------------------------
__global__ __launch_bounds__(256) void k_final_mfma(
    const float* __restrict__ aob, const float* __restrict__ xpe,
    const float* __restrict__ inter, const ushort_t* __restrict__ wfin,
    const float* __restrict__ bo,
    const float* __restrict__ gspb, const float* __restrict__ gtmb,
    const float* __restrict__ gfub,
    const float* __restrict__ g3, const float* __restrict__ b3,
    float* __restrict__ outp) {
  __shared__ ushort_t bufA[32 * 128];
  __shared__ ushort_t bufX[32 * 128];
  __shared__ ushort_t bufI[32 * 128];
  __shared__ float mpart[32][2], spart[32][2];
  char* A_ = (char*)bufA;
  char* X_ = (char*)bufX;
  char* I_ = (char*)bufI;
  int tok0 = blockIdx.x * 32;
  int tid = threadIdx.x;

  for (int seg = tid; seg < 512; seg += 256) {
    int row = seg >> 4, c8 = (seg & 15) * 8;
    int dst = (row * 256 + c8 * 2) ^ ((row & 7) << 4);
    size_t gbase = (size_t)(tok0 + row) * 128 + c8;
    {
      float4 f0 = *(const float4*)(aob + gbase);
      float4 f1 = *(const float4*)(aob + gbase + 4);
      uint4 pk = make_uint4(cvtpk_bf16(f0.x, f0.y), cvtpk_bf16(f0.z, f0.w),
                            cvtpk_bf16(f1.x, f1.y), cvtpk_bf16(f1.z, f1.w));
      *(uint4*)(A_ + dst) = pk;
    }
    {
      float4 f0 = *(const float4*)(xpe + gbase);
      float4 f1 = *(const float4*)(xpe + gbase + 4);
      uint4 pk = make_uint4(cvtpk_bf16(f0.x, f0.y), cvtpk_bf16(f0.z, f0.w),
                            cvtpk_bf16(f1.x, f1.y), cvtpk_bf16(f1.z, f1.w));
      *(uint4*)(X_ + dst) = pk;
    }
    {
      float4 f0 = *(const float4*)(inter + gbase);
      float4 f1 = *(const float4*)(inter + gbase + 4);
      uint4 pk = make_uint4(cvtpk_bf16(f0.x, f0.y), cvtpk_bf16(f0.z, f0.w),
                            cvtpk_bf16(f1.x, f1.y), cvtpk_bf16(f1.z, f1.w));
      *(uint4*)(I_ + dst) = pk;
    }
  }
  __syncthreads();

  int w = tid >> 6, lane = tid & 63;
  int i16 = lane & 15, g = lane >> 4;
  int mt = w >> 1, nh = w & 1;
  int mrow = mt * 16 + i16;

#define GATE_GEMM(ACT, WBASE, ACC)                                                            \
  {                                                                                           \
    _Pragma("unroll")                                                                         \
    for (int kt = 0; kt < 4; kt++) {                                                          \
      short8_t af = *(const short8_t*)((ACT) + ((mrow * 256 + (kt * 32 + 8 * g) * 2) ^ ((mrow & 7) << 4))); \
      _Pragma("unroll")                                                                       \
      for (int nt = 0; nt < 4; nt++) {                                                        \
        int o = nh * 64 + nt * 16 + i16;                                                      \
        short8_t bf = *(const short8_t*)(wfin + (WBASE) + (size_t)o * 256 + kt * 32 + 8 * g); \
        ACC[nt] = __builtin_amdgcn_mfma_f32_16x16x32_bf16(af, bf, ACC[nt], 0, 0, 0);          \
      }                                                                                       \
    }                                                                                         \
    _Pragma("unroll")                                                                         \
    for (int kt = 0; kt < 4; kt++) {                                                          \
      short8_t af = *(const short8_t*)(X_ + ((mrow * 256 + (kt * 32 + 8 * g) * 2) ^ ((mrow & 7) << 4))); \
      _Pragma("unroll")                                                                       \
      for (int nt = 0; nt < 4; nt++) {                                                        \
        int o = nh * 64 + nt * 16 + i16;                                                      \
        short8_t bf = *(const short8_t*)(wfin + (WBASE) + (size_t)o * 256 + 128 + kt * 32 + 8 * g); \
        ACC[nt] = __builtin_amdgcn_mfma_f32_16x16x32_bf16(af, bf, ACC[nt], 0, 0, 0);          \
      }                                                                                       \
    }                                                                                         \
  }

  float4_t accC[4];
#pragma unroll
  for (int nt = 0; nt < 4; nt++) accC[nt] = (float4_t){0.f, 0.f, 0.f, 0.f};
#pragma unroll
  for (int kt = 0; kt < 4; kt++) {
    short8_t af = *(const short8_t*)(A_ + ((mrow * 256 + (kt * 32 + 8 * g) * 2) ^ ((mrow & 7) << 4)));
#pragma unroll
    for (int nt = 0; nt < 4; nt++) {
      int o = nh * 64 + nt * 16 + i16;
      short8_t bf = *(const short8_t*)(wfin + (size_t)o * 128 + kt * 32 + 8 * g);
      accC[nt] = __builtin_amdgcn_mfma_f32_16x16x32_bf16(af, bf, accC[nt], 0, 0, 0);
    }
  }

  float4_t accIg[4];
#pragma unroll
  for (int nt = 0; nt < 4; nt++) accIg[nt] = (float4_t){0.f, 0.f, 0.f, 0.f};
  GATE_GEMM(I_, 16384, accIg);

  float crossv[4][4];
#pragma unroll
  for (int nt = 0; nt < 4; nt++) {
    float bv = bo[nh * 64 + nt * 16 + i16];
#pragma unroll
    for (int r = 0; r < 4; r++) crossv[nt][r] = accC[nt][r] + bv;
  }
  __syncthreads();
#pragma unroll
  for (int nt = 0; nt < 4; nt++) {
#pragma unroll
    for (int r = 0; r < 4; r++) {
      int trow = mt * 16 + 4 * g + r;
      int col = nh * 64 + nt * 16 + i16;
      *(ushort_t*)(A_ + ((trow * 256 + col * 2) ^ ((trow & 7) << 4))) = (ushort_t)bf16rne(crossv[nt][r]);
    }
  }
  __syncthreads();

  float4_t accCg[4];
#pragma unroll
  for (int nt = 0; nt < 4; nt++) accCg[nt] = (float4_t){0.f, 0.f, 0.f, 0.f};
  GATE_GEMM(A_, 49152, accCg);

  float comb[4][4];
#pragma unroll
  for (int nt = 0; nt < 4; nt++) {
    int o = nh * 64 + nt * 16 + i16;
    float bg1 = gspb[o], bg2 = gtmb[o];
#pragma unroll
    for (int r = 0; r < 4; r++) {
      int trow = mt * 16 + 4 * g + r;
      float iv = inter[(size_t)(tok0 + trow) * 128 + o];
      float igv = sigmoidf_(accIg[nt][r] + bg1);
      float cgv = sigmoidf_(accCg[nt][r] + bg2);
      comb[nt][r] = igv * iv + cgv * crossv[nt][r];
    }
  }
  __syncthreads();
#pragma unroll
  for (int nt = 0; nt < 4; nt++) {
#pragma unroll
    for (int r = 0; r < 4; r++) {
      int trow = mt * 16 + 4 * g + r;
      int col = nh * 64 + nt * 16 + i16;
      *(ushort_t*)(A_ + ((trow * 256 + col * 2) ^ ((trow & 7) << 4))) = (ushort_t)bf16rne(comb[nt][r]);
    }
  }
  __syncthreads();

  float4_t accFg[4];
#pragma unroll
  for (int nt = 0; nt < 4; nt++) accFg[nt] = (float4_t){0.f, 0.f, 0.f, 0.f};
  GATE_GEMM(A_, 81920, accFg);

  float outv[4][4];
  float psum[4] = {0.f, 0.f, 0.f, 0.f}, psq[4] = {0.f, 0.f, 0.f, 0.f};
#pragma unroll
  for (int nt = 0; nt < 4; nt++) {
    int o = nh * 64 + nt * 16 + i16;
    float bgf = gfub[o];
#pragma unroll
    for (int r = 0; r < 4; r++) {
      int trow = mt * 16 + 4 * g + r;
      float xv = xpe[(size_t)(tok0 + trow) * 128 + o];
      float fgv = sigmoidf_(accFg[nt][r] + bgf);
      float ov = fgv * comb[nt][r] + (1.0f - fgv) * xv;
      outv[nt][r] = ov;
      psum[r] += ov;
      psq[r] += ov * ov;
    }
  }
#pragma unroll
  for (int r = 0; r < 4; r++) {
#pragma unroll
    for (int mk = 1; mk < 16; mk <<= 1) {
      psum[r] += __shfl_xor(psum[r], mk);
      psq[r]  += __shfl_xor(psq[r], mk);
    }
  }
  if (i16 == 0) {
#pragma unroll
    for (int r = 0; r < 4; r++) {
      int tl = mt * 16 + 4 * g + r;
      mpart[tl][nh] = psum[r];
      spart[tl][nh] = psq[r];
    }
  }
  __syncthreads();
  float gv[4], bv3[4];
#pragma unroll
  for (int nt = 0; nt < 4; nt++) {
    int o = nh * 64 + nt * 16 + i16;
    gv[nt] = g3[o];
    bv3[nt] = b3[o];
  }
#pragma unroll
  for (int r = 0; r < 4; r++) {
    int tl = mt * 16 + 4 * g + r;
    float mean = (mpart[tl][0] + mpart[tl][1]) * (1.0f / 128.0f);
    float var = (spart[tl][0] + spart[tl][1]) * (1.0f / 128.0f) - mean * mean;
    float rstd = rsqrtf(var + 1e-5f);
#pragma unroll
    for (int nt = 0; nt < 4; nt++) {
      int o = nh * 64 + nt * 16 + i16;
      outp[(size_t)(tok0 + tl) * 128 + o] = (outv[nt][r] - mean) * rstd * gv[nt] + bv3[nt];
    }
  }
#undef GATE_GEMM
}

// ---------------------------------------------------------------------------
extern "C" void kernel_launch(void* const* d_in, const int* in_sizes, int n_in,
                              void* d_out, int out_size, void* d_ws, size_t ws_size,
                              hipStream_t stream) {
  (void)in_sizes; (void)n_in; (void)out_size; (void)ws_size;
  const float* x    = (const float*)d_in[0];
  const float* adj  = (const float*)d_in[1];
  const float* spos = (const float*)d_in[2];
  const float* tpos = (const float*)d_in[3];
  const float* iw   = (const float*)d_in[4];
  const float* w1   = (const float*)d_in[5];
  const float* b1   = (const float*)d_in[6];
  const float* w3   = (const float*)d_in[7];
  const float* b3   = (const float*)d_in[8];
  const float* w5   = (const float*)d_in[9];
  const float* b5   = (const float*)d_in[10];
  const float* w7   = (const float*)d_in[11];
  const float* b7   = (const float*)d_in[12];
  const float* spw0 = (const float*)d_in[13];
  const float* spb0 = (const float*)d_in[14];
  const float* spw1 = (const float*)d_in[15];
  const float* spb1 = (const float*)d_in[16];
  const float* spw2 = (const float*)d_in[17];
  const float* spb2 = (const float*)d_in[18];
  const float* wIn  = (const float*)d_in[19];
  const float* bIn  = (const float*)d_in[20];
  const float* wOut = (const float*)d_in[21];
  const float* bOut = (const float*)d_in[22];
  const float* gspw = (const float*)d_in[23];
  const float* gspb = (const float*)d_in[24];
  const float* gtmw = (const float*)d_in[25];
  const float* gtmb = (const float*)d_in[26];
  const float* gfuw = (const float*)d_in[27];
  const float* gfub = (const float*)d_in[28];
  const float* ln1g = (const float*)d_in[29];
  const float* ln1b = (const float*)d_in[30];
  const float* ln2g = (const float*)d_in[31];
  const float* ln2b = (const float*)d_in[32];
  const float* ln3g = (const float*)d_in[33];
  const float* ln3b = (const float*)d_in[34];

  float* ws = (float*)d_ws;
  float* xpe      = ws + 0 * (size_t)F_;
  float* tconv    = ws + 1 * (size_t)F_;   // reused as aob after ln1
  float* temporal = ws + 2 * (size_t)F_;
  float* spatial  = ws + 4 * (size_t)F_;
  float* inter    = ws + 5 * (size_t)F_;
  ushort_t* qb    = (ushort_t*)(ws + 6 * (size_t)F_);          // 1.5MB
  ushort_t* kbb   = qb + (size_t)16 * 3072 * 16;               // 1.5MB
  // slot 7 packing: vtb | wprep | wsp | wfin(+wqkv) | apb
  ushort_t* vtb   = (ushort_t*)(ws + 7 * (size_t)F_);          // 786432 elems
  ushort_t* wprep = vtb + (size_t)786432;                      // 262144
  ushort_t* wsp   = wprep + (size_t)262144;                    // 49152
  ushort_t* wfin  = wsp + (size_t)49152;                       // 163840 (incl. wqkv)
  ushort_t* wqkv  = wfin + (size_t)114688;
  ushort_t* apb   = wfin + (size_t)163840;                     // 9216
  float* aob = tconv;

  k_prep<<<4929, 256, 0, stream>>>(x, spos, tpos, xpe,
                                   w1, w3, w5, w7, wprep,
                                   spw0, spw1, spw2, wsp,
                                   wOut, gspw, gtmw, gfuw, wIn, wfin,
                                   adj, apb);
  k_conv_mfma<<<384, 256, 0, stream>>>(xpe, wprep, b1, b3, b5, b7, tconv);
  k_spatial_mfma<<<B_ * S_, 256, 0, stream>>>(xpe, apb, wsp, spb0, spb1, spb2,
                                              ln2g, ln2b, spatial);
  k_ln<<<TOK_ / 4, 256, 0, stream>>>(tconv, temporal, ln1g, ln1b);
  k_qkv_mfma<<<TOK_ / 32, 256, 0, stream>>>(temporal, spatial, wqkv, bIn, iw,
                                            qb, kbb, vtb, inter);
  k_attn_mfma<<<768, 256, 0, stream>>>(qb, kbb, vtb, aob);
  k_final_mfma<<<TOK_ / 32, 256, 0, stream>>>(aob, xpe, inter, wfin, bOut,
                                              gspb, gtmb, gfub, ln3g, ln3b,
                                              (float*)d_out);
}

// Round 14
// 170.649 us; speedup vs baseline: 1.0268x; 1.0268x over previous
//
#include <hip/hip_runtime.h>
#include <math.h>

typedef unsigned short ushort_t;
typedef unsigned int uint_t;
typedef float  float4_t  __attribute__((ext_vector_type(4)));
typedef short  short8_t  __attribute__((ext_vector_type(8)));
typedef short  short4_t  __attribute__((ext_vector_type(4)));

static constexpr int B_   = 2;
static constexpr int S_   = 64;
static constexpr int N_   = 48;
static constexpr int D_   = 128;
static constexpr int H_   = 8;
static constexpr int DH_  = 16;
static constexpr int L_   = S_ * N_;        // 3072
static constexpr int TOK_ = B_ * L_;        // 6144
static constexpr int F_   = TOK_ * D_;      // 786432

__device__ __forceinline__ uint_t bf16rne(float f) {
  uint_t u = __float_as_uint(f);
  return (u + 0x7fffu + ((u >> 16) & 1u)) >> 16;
}
__device__ __forceinline__ uint_t cvtpk_bf16(float lo, float hi) {
  uint_t r;
  asm("v_cvt_pk_bf16_f32 %0, %1, %2" : "=v"(r) : "v"(lo), "v"(hi));
  return r;
}
__device__ __forceinline__ float sigmoidf_(float z) {
  return 1.0f / (1.0f + __expf(-z));
}

// ---------------------------------------------------------------------------
// K0: merged prep. Block ranges (all exact multiples of 256 threads):
//   [0,3072)      posadd: xpe = x + spos + tpos
//   [3072,4096)   conv weight prep -> wprep
//   [4096,4288)   spatial weight prep -> wsp
//   [4288,4928)   final+qkv weight prep -> wfin
// ---------------------------------------------------------------------------
__global__ void k_prep(const float* __restrict__ x, const float* __restrict__ sp,
                       const float* __restrict__ tp, float* __restrict__ xpe,
                       const float* __restrict__ w1, const float* __restrict__ w3,
                       const float* __restrict__ w5, const float* __restrict__ w7,
                       ushort_t* __restrict__ wprep,
                       const float* __restrict__ sw0, const float* __restrict__ sw1,
                       const float* __restrict__ sw2, ushort_t* __restrict__ wsp,
                       const float* __restrict__ wo, const float* __restrict__ gsp,
                       const float* __restrict__ gtm, const float* __restrict__ gfu,
                       const float* __restrict__ wIn, ushort_t* __restrict__ wfin) {
  int blk = blockIdx.x;
  int tid = threadIdx.x;
  if (blk < 3072) {
    int idx = blk * 256 + tid;
    int d  = idx & 127;
    int t2 = idx >> 7;
    int n  = t2 % 48;
    int t3 = t2 / 48;
    int s  = t3 & 63;
    xpe[idx] = x[idx] + sp[n * 128 + d] + tp[s * 128 + d];
  } else if (blk < 4096) {
    int idx = (blk - 3072) * 256 + tid;    // 0..262143
    int p = idx >> 14;
    int rem = idx & 16383;
    int c = rem >> 7, i = rem & 127;
    float v;
    if (p == 0)       v = w1[c * 128 + i];
    else if (p < 4)   v = w3[(c * 128 + i) * 3 + (p - 1)];
    else if (p < 9)   v = w5[(c * 128 + i) * 5 + (p - 4)];
    else              v = w7[(c * 128 + i) * 7 + (p - 9)];
    wprep[idx] = (ushort_t)bf16rne(v);
  } else if (blk < 4288) {
    int idx = (blk - 4096) * 256 + tid;    // 0..49151
    int hop = idx >> 14, r = idx & 16383;
    const float* W = (hop == 0) ? sw0 : ((hop == 1) ? sw1 : sw2);
    wsp[idx] = (ushort_t)bf16rne(W[r]);
  } else {
    int idx = (blk - 4288) * 256 + tid;    // 0..163839
    float v;
    if (idx < 16384)       v = wo[idx];
    else if (idx < 49152)  v = gsp[idx - 16384];
    else if (idx < 81920)  v = gtm[idx - 49152];
    else if (idx < 114688) v = gfu[idx - 81920];
    else                   v = wIn[idx - 114688];
    wfin[idx] = (ushort_t)bf16rne(v);
  }
}

// ---------------------------------------------------------------------------
// K1: adjacency prep -> apb bf16 [3][48][64] (K-padded with zeros)
// ---------------------------------------------------------------------------
__global__ void k_adjprep(const float* __restrict__ adj, ushort_t* __restrict__ apb) {
  __shared__ float degl[48];
  __shared__ float a1[2304];
  __shared__ float a2[2304];
  int tid = threadIdx.x;  // 1024
  if (tid < 48) {
    float s = 0.f;
    for (int n = 0; n < 48; n++) s += adj[tid * 48 + n];
    degl[tid] = (s == 0.0f) ? 1.0f : s;
  }
  __syncthreads();
  for (int e = tid; e < 2304; e += 1024) {
    float v = adj[e] / degl[e / 48];
    a1[e] = v;
    apb[(e / 48) * 64 + (e % 48)] = (ushort_t)bf16rne(v);
  }
  __syncthreads();
  for (int e = tid; e < 2304; e += 1024) {
    int m = e / 48, n = e % 48;
    float s = 0.f;
    for (int k2 = 0; k2 < 48; k2++) s += a1[m * 48 + k2] * a1[k2 * 48 + n];
    a2[e] = s;
    apb[3072 + m * 64 + n] = (ushort_t)bf16rne(s);
  }
  __syncthreads();
  for (int e = tid; e < 2304; e += 1024) {
    int m = e / 48, n = e % 48;
    float s = 0.f;
    for (int k2 = 0; k2 < 48; k2++) s += a2[m * 48 + k2] * a1[k2 * 48 + n];
    apb[6144 + m * 64 + n] = (ushort_t)bf16rne(s);
  }
  for (int e = tid; e < 2304; e += 1024) {
    int hop = e / 768, rem = e % 768;
    apb[hop * 3072 + (rem / 16) * 64 + 48 + (rem % 16)] = 0;
  }
}

// ---------------------------------------------------------------------------
// K2: MFMA implicit-GEMM conv (unchanged, proven)
// ---------------------------------------------------------------------------
__global__ __launch_bounds__(256) void k_conv_mfma(
    const float* __restrict__ xpe, const ushort_t* __restrict__ wprep,
    const float* __restrict__ b1, const float* __restrict__ b3,
    const float* __restrict__ b5, const float* __restrict__ b7,
    float* __restrict__ out) {
  __shared__ ushort_t xl[38 * 128];
  char* xlb = (char*)xl;
  int blk = blockIdx.x;
  int bn = blk >> 2, chalf = (blk >> 1) & 1, thalf = blk & 1;
  int b = bn / 48, node = bn % 48;
  int t0 = thalf * 32;
  int tid = threadIdx.x;

  for (int seg = tid; seg < 608; seg += 256) {
    int row = seg >> 4, sidx = seg & 15;
    int gt = t0 + row - 3;
    int dst = row * 256 + ((sidx * 16) ^ ((row & 7) << 4));
    uint4 pk = make_uint4(0, 0, 0, 0);
    if (gt >= 0 && gt < 64) {
      const float* src = xpe + ((size_t)((b * 64 + gt) * 48 + node)) * 128 + sidx * 8;
      float4 f0 = ((const float4*)src)[0];
      float4 f1 = ((const float4*)src)[1];
      pk.x = bf16rne(f0.x) | (bf16rne(f0.y) << 16);
      pk.y = bf16rne(f0.z) | (bf16rne(f0.w) << 16);
      pk.z = bf16rne(f1.x) | (bf16rne(f1.y) << 16);
      pk.w = bf16rne(f1.z) | (bf16rne(f1.w) << 16);
    }
    *(uint4*)(xlb + dst) = pk;
  }
  __syncthreads();

  int w = tid >> 6, lane = tid & 63;
  int i16 = lane & 15, grp = lane >> 4;
  int grpoff = grp * 16;
  int c0 = chalf * 64 + w * 16;

  float4_t acc[4][2];
#pragma unroll
  for (int cv = 0; cv < 4; cv++)
#pragma unroll
    for (int tm = 0; tm < 2; tm++) acc[cv][tm] = (float4_t){0.f, 0.f, 0.f, 0.f};

  const int cid[16] = {0, 1, 1, 1, 2, 2, 2, 2, 2, 3, 3, 3, 3, 3, 3, 3};
  const int shf[16] = {0, -1, 0, 1, -2, -1, 0, 1, 2, -3, -2, -1, 0, 1, 2, 3};

#pragma unroll
  for (int p = 0; p < 16; p++) {
    int rb0 = 3 + shf[p] + i16;
#pragma unroll
    for (int ks = 0; ks < 4; ks++) {
      short8_t bfr = *(const short8_t*)(wprep + ((size_t)(p * 128 + c0 + i16)) * 128 + ks * 32 + grp * 8);
#pragma unroll
      for (int tm = 0; tm < 2; tm++) {
        int row = rb0 + tm * 16;
        int off = row * 256 + ((ks * 64 + grpoff) ^ ((row & 7) << 4));
        short8_t afr = *(const short8_t*)(xlb + off);
        acc[cid[p]][tm] = __builtin_amdgcn_mfma_f32_16x16x32_bf16(afr, bfr, acc[cid[p]][tm], 0, 0, 0);
      }
    }
  }

  int c = c0 + i16;
  float bias0 = b1[c], bias1 = b3[c], bias2 = b5[c], bias3 = b7[c];
#pragma unroll
  for (int tm = 0; tm < 2; tm++) {
#pragma unroll
    for (int r = 0; r < 4; r++) {
      int t = t0 + tm * 16 + grp * 4 + r;
      size_t gidx = ((size_t)((b * 64 + t) * 48 + node)) * 128 + c;
      float v = fmaxf(acc[0][tm][r] + bias0, 0.f) + fmaxf(acc[1][tm][r] + bias1, 0.f)
              + fmaxf(acc[2][tm][r] + bias2, 0.f) + fmaxf(acc[3][tm][r] + bias3, 0.f);
      out[gidx] = v * 0.25f + xpe[gidx];
    }
  }
}

// ---------------------------------------------------------------------------
// K3: combined LayerNorm launch. Blocks [0,1536): tconv->temporal (ln1);
// blocks [1536,3072): sppre->spatial (ln2). 4 rows/block (1 wave each).
// ---------------------------------------------------------------------------
__global__ void k_lnx2(const float* __restrict__ in1, float* __restrict__ out1,
                       const float* __restrict__ g1, const float* __restrict__ b1,
                       const float* __restrict__ in2, float* __restrict__ out2,
                       const float* __restrict__ g2, const float* __restrict__ b2) {
  int blk = blockIdx.x;
  const float* in  = (blk < 1536) ? in1  : in2;
  float* outp      = (blk < 1536) ? out1 : out2;
  const float* g   = (blk < 1536) ? g1   : g2;
  const float* bb  = (blk < 1536) ? b1   : b2;
  int rblk = (blk < 1536) ? blk : (blk - 1536);
  int row  = rblk * 4 + (threadIdx.x >> 6);
  int lane = threadIdx.x & 63;
  const float* r = in + row * 128;
  float v0 = r[lane], v1 = r[lane + 64];
  float s = v0 + v1;
#pragma unroll
  for (int m = 32; m; m >>= 1) s += __shfl_xor(s, m);
  float mean = s * (1.0f / 128.0f);
  float d0 = v0 - mean, d1 = v1 - mean;
  float q = d0 * d0 + d1 * d1;
#pragma unroll
  for (int m = 32; m; m >>= 1) q += __shfl_xor(q, m);
  float rstd = rsqrtf(q * (1.0f / 128.0f) + 1e-5f);
  outp[row * 128 + lane]      = d0 * rstd * g[lane]      + bb[lane];
  outp[row * 128 + lane + 64] = d1 * rstd * g[lane + 64] + bb[lane + 64];
}

// ---------------------------------------------------------------------------
// K4: MFMA spatial branch (unchanged, proven)
// ---------------------------------------------------------------------------
__global__ __launch_bounds__(256) void k_spatial_mfma(
    const float* __restrict__ xpe, const ushort_t* __restrict__ apb,
    const ushort_t* __restrict__ wsp,
    const float* __restrict__ bb0, const float* __restrict__ bb1,
    const float* __restrict__ bb2, float* __restrict__ outp) {
  __shared__ ushort_t XT[128 * 64];
  __shared__ ushort_t Cl[48 * 128];
  char* XTb = (char*)XT;
  char* Clb = (char*)Cl;
  int bs = blockIdx.x;
  int tid = threadIdx.x;
  const float* xrow = xpe + (size_t)bs * 6144;

  for (int e = tid; e < 1024; e += 256)
    *(uint4*)(XTb + e * 16) = make_uint4(0, 0, 0, 0);
  __syncthreads();
  for (int e = tid; e < 1536; e += 256) {
    int node = e % 48, dq = e / 48;
    float4 xv = *(const float4*)(xrow + node * 128 + dq * 4);
    int d0 = dq * 4;
    *(ushort_t*)(XTb + (((d0 + 0) * 128 + node * 2) ^ (((d0 + 0) & 7) << 4))) = (ushort_t)bf16rne(xv.x);
    *(ushort_t*)(XTb + (((d0 + 1) * 128 + node * 2) ^ (((d0 + 1) & 7) << 4))) = (ushort_t)bf16rne(xv.y);
    *(ushort_t*)(XTb + (((d0 + 2) * 128 + node * 2) ^ (((d0 + 2) & 7) << 4))) = (ushort_t)bf16rne(xv.z);
    *(ushort_t*)(XTb + (((d0 + 3) * 128 + node * 2) ^ (((d0 + 3) & 7) << 4))) = (ushort_t)bf16rne(xv.w);
  }
  __syncthreads();

  int w = tid >> 6, lane = tid & 63;
  int i16 = lane & 15, g = lane >> 4;

  float4_t sacc[3][2];
#pragma unroll
  for (int mt = 0; mt < 3; mt++)
#pragma unroll
    for (int nt = 0; nt < 2; nt++) sacc[mt][nt] = (float4_t){0.f, 0.f, 0.f, 0.f};

  for (int hop = 0; hop < 3; hop++) {
    float4_t c1[2][3];
#pragma unroll
    for (int mt = 0; mt < 2; mt++)
#pragma unroll
      for (int nt = 0; nt < 3; nt++) c1[mt][nt] = (float4_t){0.f, 0.f, 0.f, 0.f};
#pragma unroll
    for (int kt = 0; kt < 2; kt++) {
#pragma unroll
      for (int mt = 0; mt < 2; mt++) {
        int arow = (w * 2 + mt) * 16 + i16;
        short8_t af = *(const short8_t*)(XTb + ((arow * 128 + (kt * 32 + 8 * g) * 2) ^ ((arow & 7) << 4)));
#pragma unroll
        for (int nt = 0; nt < 3; nt++) {
          short8_t bf = *(const short8_t*)(apb + hop * 3072 + (nt * 16 + i16) * 64 + kt * 32 + 8 * g);
          c1[mt][nt] = __builtin_amdgcn_mfma_f32_16x16x32_bf16(af, bf, c1[mt][nt], 0, 0, 0);
        }
      }
    }
    __syncthreads();
#pragma unroll
    for (int mt = 0; mt < 2; mt++) {
#pragma unroll
      for (int nt = 0; nt < 3; nt++) {
        int node = nt * 16 + i16;
        int d0 = (w * 2 + mt) * 16 + 4 * g;
        uint_t lo = cvtpk_bf16(c1[mt][nt][0], c1[mt][nt][1]);
        uint_t hi = cvtpk_bf16(c1[mt][nt][2], c1[mt][nt][3]);
        *(uint2*)(Clb + ((node * 256 + d0 * 2) ^ ((node & 7) << 4))) = make_uint2(lo, hi);
      }
    }
    __syncthreads();
    float4_t c2[3][2];
#pragma unroll
    for (int mt = 0; mt < 3; mt++)
#pragma unroll
      for (int nt = 0; nt < 2; nt++) c2[mt][nt] = (float4_t){0.f, 0.f, 0.f, 0.f};
#pragma unroll
    for (int kt = 0; kt < 4; kt++) {
#pragma unroll
      for (int mt = 0; mt < 3; mt++) {
        int arow = mt * 16 + i16;
        short8_t af = *(const short8_t*)(Clb + ((arow * 256 + (kt * 32 + 8 * g) * 2) ^ ((arow & 7) << 4)));
#pragma unroll
        for (int nt = 0; nt < 2; nt++) {
          int o = (w * 2 + nt) * 16 + i16;
          short8_t bf = *(const short8_t*)(wsp + ((size_t)(hop * 128 + o)) * 128 + kt * 32 + 8 * g);
          c2[mt][nt] = __builtin_amdgcn_mfma_f32_16x16x32_bf16(af, bf, c2[mt][nt], 0, 0, 0);
        }
      }
    }
    const float* Bs = (hop == 0) ? bb0 : ((hop == 1) ? bb1 : bb2);
#pragma unroll
    for (int nt = 0; nt < 2; nt++) {
      float bi = Bs[(w * 2 + nt) * 16 + i16];
#pragma unroll
      for (int mt = 0; mt < 3; mt++)
#pragma unroll
        for (int r = 0; r < 4; r++)
          sacc[mt][nt][r] += fmaxf(c2[mt][nt][r] + bi, 0.f);
    }
  }
  float* orow = outp + (size_t)bs * 6144;
#pragma unroll
  for (int mt = 0; mt < 3; mt++) {
#pragma unroll
    for (int nt = 0; nt < 2; nt++) {
#pragma unroll
      for (int r = 0; r < 4; r++) {
        int node = mt * 16 + 4 * g + r;
        int o = (w * 2 + nt) * 16 + i16;
        orow[node * 128 + o] = sacc[mt][nt][r] * (1.0f / 3.0f) + xrow[node * 128 + o];
      }
    }
  }
}

// ---------------------------------------------------------------------------
// K6: MFMA QKV projections + fused inter (unchanged, proven)
// ---------------------------------------------------------------------------
__global__ __launch_bounds__(256) void k_qkv_mfma(
    const float* __restrict__ temporal, const float* __restrict__ spatial,
    const ushort_t* __restrict__ wqkv, const float* __restrict__ bIn,
    const float* __restrict__ iw,
    ushort_t* __restrict__ qb, ushort_t* __restrict__ kb, ushort_t* __restrict__ vtb,
    float* __restrict__ interp) {
  __shared__ ushort_t bufT[32 * 128];
  __shared__ ushort_t bufS[32 * 128];
  char* T_ = (char*)bufT;
  char* S_ = (char*)bufS;
  int tok0 = blockIdx.x * 32;
  int tid = threadIdx.x;

  for (int seg = tid; seg < 512; seg += 256) {
    int row = seg >> 4, c8 = (seg & 15) * 8;
    int dst = (row * 256 + c8 * 2) ^ ((row & 7) << 4);
    size_t gbase = (size_t)(tok0 + row) * 128 + c8;
    {
      float4 f0 = *(const float4*)(temporal + gbase);
      float4 f1 = *(const float4*)(temporal + gbase + 4);
      *(uint4*)(T_ + dst) = make_uint4(cvtpk_bf16(f0.x, f0.y), cvtpk_bf16(f0.z, f0.w),
                                       cvtpk_bf16(f1.x, f1.y), cvtpk_bf16(f1.z, f1.w));
    }
    {
      float4 f0 = *(const float4*)(spatial + gbase);
      float4 f1 = *(const float4*)(spatial + gbase + 4);
      *(uint4*)(S_ + dst) = make_uint4(cvtpk_bf16(f0.x, f0.y), cvtpk_bf16(f0.z, f0.w),
                                       cvtpk_bf16(f1.x, f1.y), cvtpk_bf16(f1.z, f1.w));
    }
  }
  __syncthreads();

  int w = tid >> 6, lane = tid & 63;
  int i16 = lane & 15, g = lane >> 4;
  int mt = w >> 1, nh = w & 1;
  int mrow = mt * 16 + i16;
  int b = tok0 / 3072, l0 = tok0 % 3072;
  const float QSCALE = 0.25f * 1.4426950408889634f;

  float4_t accQ[4], accK[4], accV[4];
#pragma unroll
  for (int nt = 0; nt < 4; nt++) {
    accQ[nt] = (float4_t){0.f, 0.f, 0.f, 0.f};
    accK[nt] = (float4_t){0.f, 0.f, 0.f, 0.f};
    accV[nt] = (float4_t){0.f, 0.f, 0.f, 0.f};
  }

#pragma unroll
  for (int kt = 0; kt < 4; kt++) {
    short8_t af = *(const short8_t*)(T_ + ((mrow * 256 + (kt * 32 + 8 * g) * 2) ^ ((mrow & 7) << 4)));
#pragma unroll
    for (int nt = 0; nt < 4; nt++) {
      int o = nh * 64 + nt * 16 + i16;
      short8_t bf = *(const short8_t*)(wqkv + (size_t)o * 128 + kt * 32 + 8 * g);
      accQ[nt] = __builtin_amdgcn_mfma_f32_16x16x32_bf16(af, bf, accQ[nt], 0, 0, 0);
    }
  }
#pragma unroll
  for (int kt = 0; kt < 4; kt++) {
    short8_t af = *(const short8_t*)(S_ + ((mrow * 256 + (kt * 32 + 8 * g) * 2) ^ ((mrow & 7) << 4)));
#pragma unroll
    for (int nt = 0; nt < 4; nt++) {
      int o = nh * 64 + nt * 16 + i16;
      short8_t bfk = *(const short8_t*)(wqkv + (size_t)(128 + o) * 128 + kt * 32 + 8 * g);
      short8_t bfv = *(const short8_t*)(wqkv + (size_t)(256 + o) * 128 + kt * 32 + 8 * g);
      accK[nt] = __builtin_amdgcn_mfma_f32_16x16x32_bf16(af, bfk, accK[nt], 0, 0, 0);
      accV[nt] = __builtin_amdgcn_mfma_f32_16x16x32_bf16(af, bfv, accV[nt], 0, 0, 0);
    }
  }

#pragma unroll
  for (int nt = 0; nt < 4; nt++) {
    int o = nh * 64 + nt * 16 + i16;
    int h = o >> 4, dh = o & 15;
    int bh = b * 8 + h;
    float bq = bIn[o], bk = bIn[128 + o], bv = bIn[256 + o];
#pragma unroll
    for (int r = 0; r < 4; r++) {
      int l = l0 + mt * 16 + 4 * g + r;
      qb[((size_t)bh * 3072 + l) * 16 + dh] = (ushort_t)bf16rne((accQ[nt][r] + bq) * QSCALE);
      kb[((size_t)bh * 3072 + l) * 16 + dh] = (ushort_t)bf16rne(accK[nt][r] + bk);
      vtb[((size_t)bh * 16 + dh) * 3072 + l] = (ushort_t)bf16rne(accV[nt][r] + bv);
    }
  }

  // fused inter: o = tid&127, token rows (tid>>7)*16 .. +15
  {
    int o = tid & 127, th = tid >> 7;
    int jb = o & ~15;
    float W[16];
    const float4* W4 = (const float4*)(iw + o * 16);
#pragma unroll
    for (int j4 = 0; j4 < 4; j4++) {
      float4 wv = W4[j4];
      W[j4 * 4 + 0] = wv.x; W[j4 * 4 + 1] = wv.y;
      W[j4 * 4 + 2] = wv.z; W[j4 * 4 + 3] = wv.w;
    }
    for (int tk = 0; tk < 16; tk++) {
      int row = th * 16 + tk;
      int sw = (row & 7) << 4;
      uint4 h0 = *(const uint4*)(S_ + ((row * 256 + jb * 2) ^ sw));
      uint4 h1 = *(const uint4*)(S_ + ((row * 256 + jb * 2 + 16) ^ sw));
      uint_t su[8] = {h0.x, h0.y, h0.z, h0.w, h1.x, h1.y, h1.z, h1.w};
      float s = 0.f;
#pragma unroll
      for (int j = 0; j < 8; j++) {
        float lo = __uint_as_float(su[j] << 16);
        float hi = __uint_as_float(su[j] & 0xFFFF0000u);
        s += W[2 * j] * lo + W[2 * j + 1] * hi;
      }
      uint_t tu = *(const ushort_t*)(T_ + ((row * 256 + o * 2) ^ sw));
      float tv = __uint_as_float((uint_t)tu << 16);
      interp[(size_t)(tok0 + row) * 128 + o] = tv * s;
    }
  }
}

// ---------------------------------------------------------------------------
// K7: MFMA flash attention v2 — VERBATIM proven version. DO NOT MODIFY.
// ---------------------------------------------------------------------------
#define ATTN_CORE(K0, K1, V0, V1)                                                    \
  {                                                                                  \
    float4_t S0 = __builtin_amdgcn_mfma_f32_16x16x32_bf16(K0, qf, (float4_t){0.f,0.f,0.f,0.f}, 0, 0, 0); \
    float4_t S1 = __builtin_amdgcn_mfma_f32_16x16x32_bf16(K1, qf, (float4_t){0.f,0.f,0.f,0.f}, 0, 0, 0); \
    float p0 = exp2f(S0[0]), p1 = exp2f(S0[1]), p2 = exp2f(S0[2]), p3 = exp2f(S0[3]); \
    float p4 = exp2f(S1[0]), p5 = exp2f(S1[1]), p6 = exp2f(S1[2]), p7 = exp2f(S1[3]); \
    lsum += ((p0 + p1) + (p2 + p3)) + ((p4 + p5) + (p6 + p7));                       \
    union { uint_t u[4]; short8_t s; } pp;                                           \
    pp.u[0] = cvtpk_bf16(p0, p1); pp.u[1] = cvtpk_bf16(p2, p3);                      \
    pp.u[2] = cvtpk_bf16(p4, p5); pp.u[3] = cvtpk_bf16(p6, p7);                      \
    union { short4_t s4[2]; short8_t s8; } vv; vv.s4[0] = V0; vv.s4[1] = V1;         \
    Ot = __builtin_amdgcn_mfma_f32_16x16x32_bf16(vv.s8, pp.s, Ot, 0, 0, 0);          \
  }

__global__ __launch_bounds__(256) void k_attn_mfma(
    const ushort_t* __restrict__ qb, const ushort_t* __restrict__ kb,
    const ushort_t* __restrict__ vtb, float* __restrict__ aob) {
  int blk = blockIdx.x;
  int bh = blk / 48, qt = blk % 48;
  int w = threadIdx.x >> 6, lane = threadIdx.x & 63;
  int i16 = lane & 15, g = lane >> 4;
  int q = qt * 64 + w * 16 + i16;

  const ushort_t* qbase = qb + (size_t)bh * 3072 * 16;
  const ushort_t* kfp = kb + (size_t)bh * 3072 * 16 + i16 * 16 + (g & 1) * 8;
  const ushort_t* vrow = vtb + ((size_t)bh * 16 + i16) * 3072 + 4 * g;

  short8_t qf = {0, 0, 0, 0, 0, 0, 0, 0};
  if (g < 2) qf = *(const short8_t*)(qbase + q * 16 + g * 8);

  float4_t Ot = {0.f, 0.f, 0.f, 0.f};
  float lsum = 0.f;

  short8_t kA0 = *(const short8_t*)(kfp + 0);
  short8_t kA1 = *(const short8_t*)(kfp + 256);
  short4_t vA0 = *(const short4_t*)(vrow + 0);
  short4_t vA1 = *(const short4_t*)(vrow + 16);
  short8_t kB0 = *(const short8_t*)(kfp + 512);
  short8_t kB1 = *(const short8_t*)(kfp + 768);
  short4_t vB0 = *(const short4_t*)(vrow + 32);
  short4_t vB1 = *(const short4_t*)(vrow + 48);

  for (int kt = 0; kt < 3072; kt += 64) {
    {
      short8_t k0 = kA0, k1 = kA1; short4_t v0 = vA0, v1 = vA1;
      int pt = kt + 64;
      kA0 = *(const short8_t*)(kfp + pt * 16);
      kA1 = *(const short8_t*)(kfp + pt * 16 + 256);
      vA0 = *(const short4_t*)(vrow + pt);
      vA1 = *(const short4_t*)(vrow + pt + 16);
      ATTN_CORE(k0, k1, v0, v1);
    }
    {
      short8_t k0 = kB0, k1 = kB1; short4_t v0 = vB0, v1 = vB1;
      int pt = kt + 96;
      kB0 = *(const short8_t*)(kfp + pt * 16);
      kB1 = *(const short8_t*)(kfp + pt * 16 + 256);
      vB0 = *(const short4_t*)(vrow + pt);
      vB1 = *(const short4_t*)(vrow + pt + 16);
      ATTN_CORE(k0, k1, v0, v1);
    }
  }

  lsum += __shfl_xor(lsum, 16);
  lsum += __shfl_xor(lsum, 32);
  float inv = 1.0f / lsum;
  int b = bh >> 3, h = bh & 7;
  float* orow = aob + ((size_t)b * 3072 + q) * 128 + h * 16;
#pragma unroll
  for (int r = 0; r < 4; r++) orow[4 * g + r] = Ot[r] * inv;
}

// ---------------------------------------------------------------------------
// K8: MFMA final stage (unchanged, proven)
// ---------------------------------------------------------------------------
__global__ __launch_bounds__(256) void k_final_mfma(
    const float* __restrict__ aob, const float* __restrict__ xpe,
    const float* __restrict__ inter, const ushort_t* __restrict__ wfin,
    const float* __restrict__ bo,
    const float* __restrict__ gspb, const float* __restrict__ gtmb,
    const float* __restrict__ gfub,
    const float* __restrict__ g3, const float* __restrict__ b3,
    float* __restrict__ outp) {
  __shared__ ushort_t bufA[32 * 128];
  __shared__ ushort_t bufX[32 * 128];
  __shared__ ushort_t bufI[32 * 128];
  __shared__ float mpart[32][2], spart[32][2];
  char* A_ = (char*)bufA;
  char* X_ = (char*)bufX;
  char* I_ = (char*)bufI;
  int tok0 = blockIdx.x * 32;
  int tid = threadIdx.x;

  for (int seg = tid; seg < 512; seg += 256) {
    int row = seg >> 4, c8 = (seg & 15) * 8;
    int dst = (row * 256 + c8 * 2) ^ ((row & 7) << 4);
    size_t gbase = (size_t)(tok0 + row) * 128 + c8;
    {
      float4 f0 = *(const float4*)(aob + gbase);
      float4 f1 = *(const float4*)(aob + gbase + 4);
      uint4 pk = make_uint4(cvtpk_bf16(f0.x, f0.y), cvtpk_bf16(f0.z, f0.w),
                            cvtpk_bf16(f1.x, f1.y), cvtpk_bf16(f1.z, f1.w));
      *(uint4*)(A_ + dst) = pk;
    }
    {
      float4 f0 = *(const float4*)(xpe + gbase);
      float4 f1 = *(const float4*)(xpe + gbase + 4);
      uint4 pk = make_uint4(cvtpk_bf16(f0.x, f0.y), cvtpk_bf16(f0.z, f0.w),
                            cvtpk_bf16(f1.x, f1.y), cvtpk_bf16(f1.z, f1.w));
      *(uint4*)(X_ + dst) = pk;
    }
    {
      float4 f0 = *(const float4*)(inter + gbase);
      float4 f1 = *(const float4*)(inter + gbase + 4);
      uint4 pk = make_uint4(cvtpk_bf16(f0.x, f0.y), cvtpk_bf16(f0.z, f0.w),
                            cvtpk_bf16(f1.x, f1.y), cvtpk_bf16(f1.z, f1.w));
      *(uint4*)(I_ + dst) = pk;
    }
  }
  __syncthreads();

  int w = tid >> 6, lane = tid & 63;
  int i16 = lane & 15, g = lane >> 4;
  int mt = w >> 1, nh = w & 1;
  int mrow = mt * 16 + i16;

#define GATE_GEMM(ACT, WBASE, ACC)                                                            \
  {                                                                                           \
    _Pragma("unroll")                                                                         \
    for (int kt = 0; kt < 4; kt++) {                                                          \
      short8_t af = *(const short8_t*)((ACT) + ((mrow * 256 + (kt * 32 + 8 * g) * 2) ^ ((mrow & 7) << 4))); \
      _Pragma("unroll")                                                                       \
      for (int nt = 0; nt < 4; nt++) {                                                        \
        int o = nh * 64 + nt * 16 + i16;                                                      \
        short8_t bf = *(const short8_t*)(wfin + (WBASE) + (size_t)o * 256 + kt * 32 + 8 * g); \
        ACC[nt] = __builtin_amdgcn_mfma_f32_16x16x32_bf16(af, bf, ACC[nt], 0, 0, 0);          \
      }                                                                                       \
    }                                                                                         \
    _Pragma("unroll")                                                                         \
    for (int kt = 0; kt < 4; kt++) {                                                          \
      short8_t af = *(const short8_t*)(X_ + ((mrow * 256 + (kt * 32 + 8 * g) * 2) ^ ((mrow & 7) << 4))); \
      _Pragma("unroll")                                                                       \
      for (int nt = 0; nt < 4; nt++) {                                                        \
        int o = nh * 64 + nt * 16 + i16;                                                      \
        short8_t bf = *(const short8_t*)(wfin + (WBASE) + (size_t)o * 256 + 128 + kt * 32 + 8 * g); \
        ACC[nt] = __builtin_amdgcn_mfma_f32_16x16x32_bf16(af, bf, ACC[nt], 0, 0, 0);          \
      }                                                                                       \
    }                                                                                         \
  }

  float4_t accC[4];
#pragma unroll
  for (int nt = 0; nt < 4; nt++) accC[nt] = (float4_t){0.f, 0.f, 0.f, 0.f};
#pragma unroll
  for (int kt = 0; kt < 4; kt++) {
    short8_t af = *(const short8_t*)(A_ + ((mrow * 256 + (kt * 32 + 8 * g) * 2) ^ ((mrow & 7) << 4)));
#pragma unroll
    for (int nt = 0; nt < 4; nt++) {
      int o = nh * 64 + nt * 16 + i16;
      short8_t bf = *(const short8_t*)(wfin + (size_t)o * 128 + kt * 32 + 8 * g);
      accC[nt] = __builtin_amdgcn_mfma_f32_16x16x32_bf16(af, bf, accC[nt], 0, 0, 0);
    }
  }

  float4_t accIg[4];
#pragma unroll
  for (int nt = 0; nt < 4; nt++) accIg[nt] = (float4_t){0.f, 0.f, 0.f, 0.f};
  GATE_GEMM(I_, 16384, accIg);

  float crossv[4][4];
#pragma unroll
  for (int nt = 0; nt < 4; nt++) {
    float bv = bo[nh * 64 + nt * 16 + i16];
#pragma unroll
    for (int r = 0; r < 4; r++) crossv[nt][r] = accC[nt][r] + bv;
  }
  __syncthreads();
#pragma unroll
  for (int nt = 0; nt < 4; nt++) {
#pragma unroll
    for (int r = 0; r < 4; r++) {
      int trow = mt * 16 + 4 * g + r;
      int col = nh * 64 + nt * 16 + i16;
      *(ushort_t*)(A_ + ((trow * 256 + col * 2) ^ ((trow & 7) << 4))) = (ushort_t)bf16rne(crossv[nt][r]);
    }
  }
  __syncthreads();

  float4_t accCg[4];
#pragma unroll
  for (int nt = 0; nt < 4; nt++) accCg[nt] = (float4_t){0.f, 0.f, 0.f, 0.f};
  GATE_GEMM(A_, 49152, accCg);

  float comb[4][4];
#pragma unroll
  for (int nt = 0; nt < 4; nt++) {
    int o = nh * 64 + nt * 16 + i16;
    float bg1 = gspb[o], bg2 = gtmb[o];
#pragma unroll
    for (int r = 0; r < 4; r++) {
      int trow = mt * 16 + 4 * g + r;
      float iv = inter[(size_t)(tok0 + trow) * 128 + o];
      float igv = sigmoidf_(accIg[nt][r] + bg1);
      float cgv = sigmoidf_(accCg[nt][r] + bg2);
      comb[nt][r] = igv * iv + cgv * crossv[nt][r];
    }
  }
  __syncthreads();
#pragma unroll
  for (int nt = 0; nt < 4; nt++) {
#pragma unroll
    for (int r = 0; r < 4; r++) {
      int trow = mt * 16 + 4 * g + r;
      int col = nh * 64 + nt * 16 + i16;
      *(ushort_t*)(A_ + ((trow * 256 + col * 2) ^ ((trow & 7) << 4))) = (ushort_t)bf16rne(comb[nt][r]);
    }
  }
  __syncthreads();

  float4_t accFg[4];
#pragma unroll
  for (int nt = 0; nt < 4; nt++) accFg[nt] = (float4_t){0.f, 0.f, 0.f, 0.f};
  GATE_GEMM(A_, 81920, accFg);

  float outv[4][4];
  float psum[4] = {0.f, 0.f, 0.f, 0.f}, psq[4] = {0.f, 0.f, 0.f, 0.f};
#pragma unroll
  for (int nt = 0; nt < 4; nt++) {
    int o = nh * 64 + nt * 16 + i16;
    float bgf = gfub[o];
#pragma unroll
    for (int r = 0; r < 4; r++) {
      int trow = mt * 16 + 4 * g + r;
      float xv = xpe[(size_t)(tok0 + trow) * 128 + o];
      float fgv = sigmoidf_(accFg[nt][r] + bgf);
      float ov = fgv * comb[nt][r] + (1.0f - fgv) * xv;
      outv[nt][r] = ov;
      psum[r] += ov;
      psq[r] += ov * ov;
    }
  }
#pragma unroll
  for (int r = 0; r < 4; r++) {
#pragma unroll
    for (int mk = 1; mk < 16; mk <<= 1) {
      psum[r] += __shfl_xor(psum[r], mk);
      psq[r]  += __shfl_xor(psq[r], mk);
    }
  }
  if (i16 == 0) {
#pragma unroll
    for (int r = 0; r < 4; r++) {
      int tl = mt * 16 + 4 * g + r;
      mpart[tl][nh] = psum[r];
      spart[tl][nh] = psq[r];
    }
  }
  __syncthreads();
  float gv[4], bv3[4];
#pragma unroll
  for (int nt = 0; nt < 4; nt++) {
    int o = nh * 64 + nt * 16 + i16;
    gv[nt] = g3[o];
    bv3[nt] = b3[o];
  }
#pragma unroll
  for (int r = 0; r < 4; r++) {
    int tl = mt * 16 + 4 * g + r;
    float mean = (mpart[tl][0] + mpart[tl][1]) * (1.0f / 128.0f);
    float var = (spart[tl][0] + spart[tl][1]) * (1.0f / 128.0f) - mean * mean;
    float rstd = rsqrtf(var + 1e-5f);
#pragma unroll
    for (int nt = 0; nt < 4; nt++) {
      int o = nh * 64 + nt * 16 + i16;
      outp[(size_t)(tok0 + tl) * 128 + o] = (outv[nt][r] - mean) * rstd * gv[nt] + bv3[nt];
    }
  }
#undef GATE_GEMM
}

// ---------------------------------------------------------------------------
extern "C" void kernel_launch(void* const* d_in, const int* in_sizes, int n_in,
                              void* d_out, int out_size, void* d_ws, size_t ws_size,
                              hipStream_t stream) {
  (void)in_sizes; (void)n_in; (void)out_size; (void)ws_size;
  const float* x    = (const float*)d_in[0];
  const float* adj  = (const float*)d_in[1];
  const float* spos = (const float*)d_in[2];
  const float* tpos = (const float*)d_in[3];
  const float* iw   = (const float*)d_in[4];
  const float* w1   = (const float*)d_in[5];
  const float* b1   = (const float*)d_in[6];
  const float* w3   = (const float*)d_in[7];
  const float* b3   = (const float*)d_in[8];
  const float* w5   = (const float*)d_in[9];
  const float* b5   = (const float*)d_in[10];
  const float* w7   = (const float*)d_in[11];
  const float* b7   = (const float*)d_in[12];
  const float* spw0 = (const float*)d_in[13];
  const float* spb0 = (const float*)d_in[14];
  const float* spw1 = (const float*)d_in[15];
  const float* spb1 = (const float*)d_in[16];
  const float* spw2 = (const float*)d_in[17];
  const float* spb2 = (const float*)d_in[18];
  const float* wIn  = (const float*)d_in[19];
  const float* bIn  = (const float*)d_in[20];
  const float* wOut = (const float*)d_in[21];
  const float* bOut = (const float*)d_in[22];
  const float* gspw = (const float*)d_in[23];
  const float* gspb = (const float*)d_in[24];
  const float* gtmw = (const float*)d_in[25];
  const float* gtmb = (const float*)d_in[26];
  const float* gfuw = (const float*)d_in[27];
  const float* gfub = (const float*)d_in[28];
  const float* ln1g = (const float*)d_in[29];
  const float* ln1b = (const float*)d_in[30];
  const float* ln2g = (const float*)d_in[31];
  const float* ln2b = (const float*)d_in[32];
  const float* ln3g = (const float*)d_in[33];
  const float* ln3b = (const float*)d_in[34];

  float* ws = (float*)d_ws;
  float* xpe      = ws + 0 * (size_t)F_;
  float* tconv    = ws + 1 * (size_t)F_;   // reused as aob after ln1
  float* temporal = ws + 2 * (size_t)F_;
  float* sppre    = ws + 3 * (size_t)F_;
  float* spatial  = ws + 4 * (size_t)F_;
  float* inter    = ws + 5 * (size_t)F_;
  ushort_t* qb    = (ushort_t*)(ws + 6 * (size_t)F_);          // 1.5MB
  ushort_t* kbb   = qb + (size_t)16 * 3072 * 16;               // 1.5MB
  // slot 7 packing: vtb | wprep | wsp | wfin(+wqkv) | apb
  ushort_t* vtb   = (ushort_t*)(ws + 7 * (size_t)F_);          // 786432 elems
  ushort_t* wprep = vtb + (size_t)786432;                      // 262144
  ushort_t* wsp   = wprep + (size_t)262144;                    // 49152
  ushort_t* wfin  = wsp + (size_t)49152;                       // 163840 (incl. wqkv)
  ushort_t* wqkv  = wfin + (size_t)114688;
  ushort_t* apb   = wfin + (size_t)163840;                     // 9216
  float* aob = tconv;

  k_prep<<<4928, 256, 0, stream>>>(x, spos, tpos, xpe,
                                   w1, w3, w5, w7, wprep,
                                   spw0, spw1, spw2, wsp,
                                   wOut, gspw, gtmw, gfuw, wIn, wfin);
  k_adjprep<<<1, 1024, 0, stream>>>(adj, apb);
  k_conv_mfma<<<384, 256, 0, stream>>>(xpe, wprep, b1, b3, b5, b7, tconv);
  k_spatial_mfma<<<B_ * S_, 256, 0, stream>>>(xpe, apb, wsp, spb0, spb1, spb2, sppre);
  k_lnx2<<<3072, 256, 0, stream>>>(tconv, temporal, ln1g, ln1b,
                                   sppre, spatial, ln2g, ln2b);
  k_qkv_mfma<<<TOK_ / 32, 256, 0, stream>>>(temporal, spatial, wqkv, bIn, iw,
                                            qb, kbb, vtb, inter);
  k_attn_mfma<<<768, 256, 0, stream>>>(qb, kbb, vtb, aob);
  k_final_mfma<<<TOK_ / 32, 256, 0, stream>>>(aob, xpe, inter, wfin, bOut,
                                              gspb, gtmb, gfub, ln3g, ln3b,
                                              (float*)d_out);
}